// Round 1
// baseline (325.372 us; speedup 1.0000x reference)
//
#include <hip/hip_runtime.h>
#include <hip/hip_bf16.h>
#include <stdint.h>

typedef __bf16 bf16;
typedef __attribute__((ext_vector_type(8))) __bf16 bf16x8;
typedef __attribute__((ext_vector_type(4))) float f32x4;

#define KREAL 784
#define KPAD  800

// ---------------------------------------------------------------------------
// Prep: fold 3x3 VALID cross-correlation into w1.
// W1t[n][k] = sum_{di,dj} w_conv[di,dj] * w1[(r-di)*26 + (c-dj)][n],  k=(r,c)
// Stored TRANSPOSED (n-major, k contiguous, padded to 800) as bf16 so the
// GEMM's B-fragment loads are contiguous ds_read_b128.
// ---------------------------------------------------------------------------
__global__ __launch_bounds__(256) void prep_w1t(const float* __restrict__ w_conv,
                                                const float* __restrict__ w1,
                                                bf16* __restrict__ W1t) {
    const int k = blockIdx.x;    // 0..799
    const int n = threadIdx.x;   // 0..255
    float s = 0.0f;
    if (k < KREAL) {
        const int r = k / 28, c = k % 28;
        #pragma unroll
        for (int di = 0; di < 3; ++di) {
            const int i = r - di;
            if (i < 0 || i >= 26) continue;
            #pragma unroll
            for (int dj = 0; dj < 3; ++dj) {
                const int j = c - dj;
                if (j < 0 || j >= 26) continue;
                s += w_conv[di * 3 + dj] * w1[(i * 26 + j) * 256 + n];
            }
        }
    }
    W1t[n * KPAD + k] = (bf16)s;   // pad region k>=784 gets 0
}

// ---------------------------------------------------------------------------
// Fused: out = relu(x @ W1' + b1) @ w2 + b2
// Tile: M=128 rows/block, N=256 (full), BK=32. 4 waves, each wave owns
// 32 rows x 256 cols -> acc[2][16] f32x4 (128 VGPRs). Epilogue does the
// 256->10 GEMM on fp32 VALU with a 16-lane shfl_xor butterfly per row.
// ---------------------------------------------------------------------------
__global__ __launch_bounds__(256, 2) void fused_mlp(
    const float* __restrict__ x,    // (65536, 784)
    const bf16*  __restrict__ W1t,  // (256, 800) bf16, transposed W1'
    const float* __restrict__ b1,   // (256)
    const float* __restrict__ w2,   // (256, 10)
    const float* __restrict__ b2,   // (10)
    float* __restrict__ out)        // (65536, 10)
{
    __shared__ bf16  As[128][32];   // [m][k]  8 KB
    __shared__ bf16  Bs[256][32];   // [n][k] 16 KB
    __shared__ float w2s[256][10];  // 10 KB
    __shared__ float b1s[256];
    __shared__ float b2s[10];

    const int t    = threadIdx.x;
    const int wave = t >> 6;
    const int lane = t & 63;
    const int c    = lane & 15;   // MFMA col within 16-tile
    const int q    = lane >> 4;   // MFMA quad

    const int row0 = blockIdx.x * 128;

    // one-time stages (visible after first loop barrier)
    for (int i = t; i < 2560; i += 256) ((float*)w2s)[i] = w2[i];
    b1s[t] = b1[t];
    if (t < 10) b2s[t] = b2[t];

    // A staging: thread -> (row, 16-float half)
    const int arow  = t >> 1;
    const int ahalf = t & 1;
    const float* xsrc = x + (size_t)(row0 + arow) * KREAL + ahalf * 16;
    // B staging: thread t owns Bs row t (32 bf16 = 64 B)
    const bf16* bsrc = W1t + t * KPAD;

    f32x4 acc[2][16];
    #pragma unroll
    for (int mt = 0; mt < 2; ++mt)
        #pragma unroll
        for (int nt = 0; nt < 16; ++nt)
            acc[mt][nt] = (f32x4){0.f, 0.f, 0.f, 0.f};

    #pragma unroll 1
    for (int k0 = 0; k0 < KPAD; k0 += 32) {
        // ---- global loads into registers (before barrier) ----
        float4 av0, av1, av2, av3;
        const bool valid = (k0 + ahalf * 16) < KREAL;  // 784 = 24*32+16: half-granular
        const float4* a4 = (const float4*)(xsrc + k0);
        if (valid) { av0 = a4[0]; av1 = a4[1]; av2 = a4[2]; av3 = a4[3]; }
        else       { av0 = av1 = av2 = av3 = (float4){0.f, 0.f, 0.f, 0.f}; }
        const uint4* b4 = (const uint4*)(bsrc + k0);
        uint4 bv0 = b4[0], bv1 = b4[1], bv2 = b4[2], bv3 = b4[3];

        __syncthreads();  // previous iter's LDS reads complete

        // ---- LDS stores ----
        bf16x8 p0, p1;
        p0[0] = (bf16)av0.x; p0[1] = (bf16)av0.y; p0[2] = (bf16)av0.z; p0[3] = (bf16)av0.w;
        p0[4] = (bf16)av1.x; p0[5] = (bf16)av1.y; p0[6] = (bf16)av1.z; p0[7] = (bf16)av1.w;
        p1[0] = (bf16)av2.x; p1[1] = (bf16)av2.y; p1[2] = (bf16)av2.z; p1[3] = (bf16)av2.w;
        p1[4] = (bf16)av3.x; p1[5] = (bf16)av3.y; p1[6] = (bf16)av3.z; p1[7] = (bf16)av3.w;
        *(bf16x8*)&As[arow][ahalf * 16]     = p0;
        *(bf16x8*)&As[arow][ahalf * 16 + 8] = p1;
        *(uint4*)&Bs[t][0]  = bv0;
        *(uint4*)&Bs[t][8]  = bv1;
        *(uint4*)&Bs[t][16] = bv2;
        *(uint4*)&Bs[t][24] = bv3;

        __syncthreads();

        // ---- MFMA: A[m= lane&15][k=q*8+j], B[k=q*8+j][n=lane&15] ----
        bf16x8 a0 = *(const bf16x8*)&As[wave * 32 +      c][q * 8];
        bf16x8 a1 = *(const bf16x8*)&As[wave * 32 + 16 + c][q * 8];
        #pragma unroll
        for (int nt = 0; nt < 16; ++nt) {
            bf16x8 b = *(const bf16x8*)&Bs[nt * 16 + c][q * 8];
            acc[0][nt] = __builtin_amdgcn_mfma_f32_16x16x32_bf16(a0, b, acc[0][nt], 0, 0, 0);
            acc[1][nt] = __builtin_amdgcn_mfma_f32_16x16x32_bf16(a1, b, acc[1][nt], 0, 0, 0);
        }
    }

    // ---- epilogue: h = relu(acc + b1); out = h @ w2 + b2 ----
    // C/D layout: col = lane&15 (= n within tile), row = q*4 + reg
    float bl[16];
    #pragma unroll
    for (int nt = 0; nt < 16; ++nt) bl[nt] = b1s[nt * 16 + c];

    #pragma unroll
    for (int mt = 0; mt < 2; ++mt)
        #pragma unroll
        for (int nt = 0; nt < 16; ++nt)
            #pragma unroll
            for (int r = 0; r < 4; ++r) {
                float v = acc[mt][nt][r] + bl[nt];
                acc[mt][nt][r] = v > 0.f ? v : 0.f;
            }

    #pragma unroll 1
    for (int j = 0; j < 10; ++j) {
        float wj[16];
        #pragma unroll
        for (int nt = 0; nt < 16; ++nt) wj[nt] = w2s[nt * 16 + c][j];
        const float b2j = b2s[j];
        #pragma unroll
        for (int mt = 0; mt < 2; ++mt)
            #pragma unroll
            for (int r = 0; r < 4; ++r) {
                float s = 0.f;
                #pragma unroll
                for (int nt = 0; nt < 16; ++nt) s += acc[mt][nt][r] * wj[nt];
                // reduce over the 16 lanes (c=0..15) holding this row's cols
                s += __shfl_xor(s, 1, 64);
                s += __shfl_xor(s, 2, 64);
                s += __shfl_xor(s, 4, 64);
                s += __shfl_xor(s, 8, 64);
                if (c == j) {
                    const int row = row0 + wave * 32 + mt * 16 + q * 4 + r;
                    out[(size_t)row * 10 + j] = s + b2j;
                }
            }
    }
}

extern "C" void kernel_launch(void* const* d_in, const int* in_sizes, int n_in,
                              void* d_out, int out_size, void* d_ws, size_t ws_size,
                              hipStream_t stream) {
    const float* x  = (const float*)d_in[0];
    const float* wc = (const float*)d_in[1];
    const float* w1 = (const float*)d_in[2];
    const float* b1 = (const float*)d_in[3];
    const float* w2 = (const float*)d_in[4];
    const float* b2 = (const float*)d_in[5];
    float* out = (float*)d_out;
    bf16* W1t = (bf16*)d_ws;  // 256*800*2 = 400 KB scratch

    prep_w1t<<<dim3(KPAD), dim3(256), 0, stream>>>(wc, w1, W1t);
    fused_mlp<<<dim3(65536 / 128), dim3(256), 0, stream>>>(x, W1t, b1, w2, b2, out);
}

// Round 2
// 317.945 us; speedup vs baseline: 1.0234x; 1.0234x over previous
//
#include <hip/hip_runtime.h>
#include <hip/hip_bf16.h>
#include <stdint.h>

typedef __bf16 bf16;
typedef __attribute__((ext_vector_type(8))) __bf16 bf16x8;
typedef __attribute__((ext_vector_type(4))) float f32x4;

#define KREAL 784
#define KPAD  800

#define GLOBAL_AS __attribute__((address_space(1)))
#define LDS_AS    __attribute__((address_space(3)))

// ---------------------------------------------------------------------------
// Prep: fold 3x3 VALID cross-correlation into w1.
// W1t[n][k] = sum_{di,dj} w_conv[di,dj] * w1[(r-di)*26 + (c-dj)][n],  k=(r,c)
// Stored TRANSPOSED (n-major, k contiguous, padded to 800) as bf16.
// ---------------------------------------------------------------------------
__global__ __launch_bounds__(256) void prep_w1t(const float* __restrict__ w_conv,
                                                const float* __restrict__ w1,
                                                bf16* __restrict__ W1t) {
    const int k = blockIdx.x;    // 0..799
    const int n = threadIdx.x;   // 0..255
    float s = 0.0f;
    if (k < KREAL) {
        const int r = k / 28, c = k % 28;
        #pragma unroll
        for (int di = 0; di < 3; ++di) {
            const int i = r - di;
            if (i < 0 || i >= 26) continue;
            #pragma unroll
            for (int dj = 0; dj < 3; ++dj) {
                const int j = c - dj;
                if (j < 0 || j >= 26) continue;
                s += w_conv[di * 3 + dj] * w1[(i * 26 + j) * 256 + n];
            }
        }
    }
    W1t[n * KPAD + k] = (bf16)s;   // pad region k>=784 gets 0
}

// ---------------------------------------------------------------------------
// Fused: out = relu(x @ W1' + b1) @ w2 + b2
// M=128/block, N=256 (full), BK=32. A-fragments: global -> regs directly
// (no LDS, no barrier coupling of the HBM stream). B: global_load_lds DMA
// into Bs[256][32], shared by the 4 waves. Epilogue: 256->10 on fp32 VALU
// with a 16-lane shfl_xor butterfly.
// ---------------------------------------------------------------------------
__global__ __launch_bounds__(256, 2) void fused_mlp(
    const float* __restrict__ x,    // (65536, 784)
    const bf16*  __restrict__ W1t,  // (256, 800) bf16
    const float* __restrict__ b1,   // (256)
    const float* __restrict__ w2,   // (256, 10)
    const float* __restrict__ b2,   // (10)
    float* __restrict__ out)        // (65536, 10)
{
    __shared__ bf16  Bs[256][32];   // [n][k] 16 KB
    __shared__ float w2s[256][10];  // 10 KB
    __shared__ float b1s[256];
    __shared__ float b2s[10];

    const int t    = threadIdx.x;
    const int wave = t >> 6;
    const int lane = t & 63;
    const int c    = lane & 15;   // MFMA col / A-row within 16-tile
    const int q    = lane >> 4;   // MFMA quad (k-chunk selector)

    const int row0 = blockIdx.x * 128;

    // one-time stages (visible after first loop barrier)
    for (int i = t; i < 2560; i += 256) ((float*)w2s)[i] = w2[i];
    b1s[t] = b1[t];
    if (t < 10) b2s[t] = b2[t];

    // A: lane (c,q) owns rows (wave*32 + c) and (+16), k-chunk q*8..q*8+7
    const float* arow0 = x + (size_t)(row0 + wave * 32 + c) * KREAL + q * 8;
    const float* arow1 = arow0 + (size_t)16 * KREAL;

    // B DMA: per-wave instr j stages Bs rows (wave*4+j)*16 .. +15 (1 KB each).
    // LDS dst = base + lane*16 (HW rule) == Bs[(wave*4+j)*16 + (lane>>2)][ (lane&3)*8 ]
    const bf16* bsrc0 = W1t + (size_t)(wave * 64 + (lane >> 2)) * KPAD + (lane & 3) * 8;
    char* bdst0 = (char*)(&Bs[0][0]) + wave * 4096;

    f32x4 acc[2][16];
    #pragma unroll
    for (int mt = 0; mt < 2; ++mt)
        #pragma unroll
        for (int nt = 0; nt < 16; ++nt)
            acc[mt][nt] = (f32x4){0.f, 0.f, 0.f, 0.f};

    #pragma unroll 1
    for (int k0 = 0; k0 < KPAD; k0 += 32) {
        __syncthreads();  // Bs consumed by previous iteration

        // ---- B: async DMA global -> LDS (4 x 1KB per wave) ----
        #pragma unroll
        for (int j = 0; j < 4; ++j) {
            __builtin_amdgcn_global_load_lds(
                (const GLOBAL_AS void*)(bsrc0 + k0 + j * 16 * KPAD),
                (LDS_AS void*)(bdst0 + j * 1024), 16, 0, 0);
        }

        // ---- A: global -> regs, convert to bf16 ----
        float4 f0a, f0b, f1a, f1b;
        if (k0 + q * 8 < KREAL) {   // 784 % 8 == 0: chunk fully in or out
            const float* p0 = arow0 + k0;
            const float* p1 = arow1 + k0;
            f0a = *(const float4*)p0; f0b = *(const float4*)(p0 + 4);
            f1a = *(const float4*)p1; f1b = *(const float4*)(p1 + 4);
        } else {
            f0a = f0b = f1a = f1b = (float4){0.f, 0.f, 0.f, 0.f};
        }
        bf16x8 a0, a1;
        a0[0] = (bf16)f0a.x; a0[1] = (bf16)f0a.y; a0[2] = (bf16)f0a.z; a0[3] = (bf16)f0a.w;
        a0[4] = (bf16)f0b.x; a0[5] = (bf16)f0b.y; a0[6] = (bf16)f0b.z; a0[7] = (bf16)f0b.w;
        a1[0] = (bf16)f1a.x; a1[1] = (bf16)f1a.y; a1[2] = (bf16)f1a.z; a1[3] = (bf16)f1a.w;
        a1[4] = (bf16)f1b.x; a1[5] = (bf16)f1b.y; a1[6] = (bf16)f1b.z; a1[7] = (bf16)f1b.w;

        __syncthreads();  // DMA complete (vmcnt drain) -> Bs valid

        // ---- MFMA: A[m=c][k=q*8+j], B[n=c][k=q*8+j] ----
        #pragma unroll
        for (int nt = 0; nt < 16; ++nt) {
            bf16x8 b = *(const bf16x8*)&Bs[nt * 16 + c][q * 8];
            acc[0][nt] = __builtin_amdgcn_mfma_f32_16x16x32_bf16(a0, b, acc[0][nt], 0, 0, 0);
            acc[1][nt] = __builtin_amdgcn_mfma_f32_16x16x32_bf16(a1, b, acc[1][nt], 0, 0, 0);
        }
    }

    // ---- epilogue: h = relu(acc + b1); out = h @ w2 + b2 ----
    // C/D layout: col = lane&15 (= n within tile), row = q*4 + reg
    float bl[16];
    #pragma unroll
    for (int nt = 0; nt < 16; ++nt) bl[nt] = b1s[nt * 16 + c];

    #pragma unroll
    for (int mt = 0; mt < 2; ++mt)
        #pragma unroll
        for (int nt = 0; nt < 16; ++nt)
            #pragma unroll
            for (int r = 0; r < 4; ++r) {
                float v = acc[mt][nt][r] + bl[nt];
                acc[mt][nt][r] = v > 0.f ? v : 0.f;
            }

    #pragma unroll 1
    for (int j = 0; j < 10; ++j) {
        float wj[16];
        #pragma unroll
        for (int nt = 0; nt < 16; ++nt) wj[nt] = w2s[nt * 16 + c][j];
        const float b2j = b2s[j];
        #pragma unroll
        for (int mt = 0; mt < 2; ++mt)
            #pragma unroll
            for (int r = 0; r < 4; ++r) {
                float s = 0.f;
                #pragma unroll
                for (int nt = 0; nt < 16; ++nt) s += acc[mt][nt][r] * wj[nt];
                s += __shfl_xor(s, 1, 64);
                s += __shfl_xor(s, 2, 64);
                s += __shfl_xor(s, 4, 64);
                s += __shfl_xor(s, 8, 64);
                if (c == j) {
                    const int row = row0 + wave * 32 + mt * 16 + q * 4 + r;
                    out[(size_t)row * 10 + j] = s + b2j;
                }
            }
    }
}

extern "C" void kernel_launch(void* const* d_in, const int* in_sizes, int n_in,
                              void* d_out, int out_size, void* d_ws, size_t ws_size,
                              hipStream_t stream) {
    const float* x  = (const float*)d_in[0];
    const float* wc = (const float*)d_in[1];
    const float* w1 = (const float*)d_in[2];
    const float* b1 = (const float*)d_in[3];
    const float* w2 = (const float*)d_in[4];
    const float* b2 = (const float*)d_in[5];
    float* out = (float*)d_out;
    bf16* W1t = (bf16*)d_ws;  // 256*800*2 = 400 KB scratch

    prep_w1t<<<dim3(KPAD), dim3(256), 0, stream>>>(wc, w1, W1t);
    fused_mlp<<<dim3(65536 / 128), dim3(256), 0, stream>>>(x, W1t, b1, w2, b2, out);
}